// Round 9
// baseline (291.975 us; speedup 1.0000x reference)
//
#include <hip/hip_runtime.h>

// Problem constants (B=4, S=4096, D_MODEL=1024, H*Dk=H*Dv=1024)
#define M_TOT 16384
#define DM    1024

typedef unsigned short ushort_t;
typedef __bf16 bf16x8 __attribute__((ext_vector_type(8)));
typedef float  f32x4  __attribute__((ext_vector_type(4)));

__device__ __forceinline__ ushort_t f32_to_bf16(float f) {
    union { float f; unsigned u; } v; v.f = f;
    unsigned u = v.u;
    return (ushort_t)((u + 0x7fffu + ((u >> 16) & 1u)) >> 16);   // RNE
}
__device__ __forceinline__ float bf16_to_f32(ushort_t h) {
    union { unsigned u; float f; } v; v.u = ((unsigned)h) << 16;
    return v.f;
}

// async global->LDS, 16B per lane; LDS dest is wave-uniform base + lane*16
__device__ __forceinline__ void gload16(const ushort_t* g, ushort_t* l) {
    __builtin_amdgcn_global_load_lds(
        (const __attribute__((address_space(1))) unsigned int*)g,
        (__attribute__((address_space(3))) unsigned int*)l,
        16, 0, 0);
}

// ---------------- fp32 -> bf16 conversion, k-tiled, FULLY COALESCED ----------------
// Outputs [K/32][rows][32] planes (r8 layout). r8 wrote 16 B/lane at 64-B
// stride (4x write waste); here thread <-> 16-B-output-chunk mapping makes
// writes contiguous across lanes. Reads: 2x float4 per thread.
// wcat keeps the 16-row v/g interleave (v rows p*32+r, g rows p*32+16+r).
__global__ __launch_bounds__(256) void cvt_all(const float* __restrict__ x,
                                               const float* __restrict__ wv,
                                               const float* __restrict__ wg,
                                               const float* __restrict__ wo,
                                               ushort_t* __restrict__ xkt,
                                               ushort_t* __restrict__ wcat,
                                               ushort_t* __restrict__ wob) {
    const long CX = (long)M_TOT * DM / 8;       // 2,097,152 8-elem chunks
    const long CW = (long)2 * DM * DM / 8;      //   262,144
    long t = (long)blockIdx.x * 256 + threadIdx.x;
    const float* src; ushort_t* dst; long soff, doff;
    if (t < CX) {
        long q = t;
        int c = (int)(q & 3);
        int row = (int)((q >> 2) & (M_TOT - 1));
        int plane = (int)(q >> 16);             // 4*M_TOT = 65536 chunks/plane
        soff = (long)row * DM + plane * 32 + c * 8;
        doff = ((long)plane * M_TOT + row) * 32 + c * 8;
        src = x; dst = xkt;
    } else if (t < CX + CW) {
        long q = t - CX;
        int c = (int)(q & 3);
        int orow = (int)((q >> 2) & 2047);
        int plane = (int)(q >> 13);             // 4*2048 chunks/plane
        int srow = ((orow >> 5) << 4) | (orow & 15);
        src = (orow & 16) ? wg : wv;
        soff = (long)srow * DM + plane * 32 + c * 8;
        doff = ((long)plane * 2048 + orow) * 32 + c * 8;
        dst = wcat;
    } else {
        long q = t - CX - CW;
        int c = (int)(q & 3);
        int row = (int)((q >> 2) & 1023);
        int plane = (int)(q >> 12);             // 4*1024 chunks/plane
        soff = (long)row * DM + plane * 32 + c * 8;
        doff = ((long)plane * DM + row) * 32 + c * 8;
        src = wo; dst = wob;
    }
    const float4 a = *(const float4*)(src + soff);
    const float4 b = *(const float4*)(src + soff + 4);
    union { ushort_t u[8]; int4 v; } o;
    o.u[0] = f32_to_bf16(a.x); o.u[1] = f32_to_bf16(a.y);
    o.u[2] = f32_to_bf16(a.z); o.u[3] = f32_to_bf16(a.w);
    o.u[4] = f32_to_bf16(b.x); o.u[5] = f32_to_bf16(b.y);
    o.u[6] = f32_to_bf16(b.z); o.u[7] = f32_to_bf16(b.w);
    *(int4*)(dst + doff) = o.v;
}

// ---------------- r8 K-loop + COALESCED LDS-bounce epilogues ----------------
// K-loop is r8 verbatim (refcheck'd): BM=BN=256, 512 threads (8 waves,
// 2M x 4N), 16x16x32 MFMA, acc[8][4]; K = 32 units of 32; LDS 128 KB ring of
// 4 slots, fragment-tiled 1-KB lane-linear frags (0 conflicts); stage-ahead 3,
// counted vmcnt(8) -> 4 -> 0; k-tiled operand planes (full-line staging).
// NEW (r8 post-mortem): epilogues were 2-B scatter (gemm<1>: 128 loads + 128
// stores per thread -> its 2.3x per-unit anomaly). Now: acc -> XOR-swizzled
// LDS bf16 tile -> barrier -> int4-coalesced global stream-out.
// EPI=0: gated = v*silu(g), 256x128 bf16 bounce (64 KB) -> k-tiled gated.
// EPI=1: proj (no residual; LN adds it), 256x256 bf16 bounce (128 KB)
//        -> row-major proj.
template<int EPI, int NB>
__global__ __launch_bounds__(512, 2) void gemmS(
    const ushort_t* __restrict__ A,    // k-tiled [32][M_TOT][32]
    const ushort_t* __restrict__ Bm,   // k-tiled [32][NB][32]
    ushort_t* __restrict__ out0,
    int nbs)                           // log2(n-blocks per XCD stripe)
{
    extern __shared__ ushort_t lds[];   // 65536 ushorts = 128 KB

    const int flat = blockIdx.x;
    const int xcd  = flat & 7;
    const int ii   = flat >> 3;
    const int m0   = ((xcd << 3) + (ii >> nbs)) << 8;
    const int n0   = (ii & ((1 << nbs) - 1)) << 8;

    const int tid  = threadIdx.x;
    const int w    = tid >> 6;         // wave 0..7
    const int l    = tid & 63;
    const int wm   = w >> 2;           // 0..1 (M)
    const int wn   = w & 3;            // 0..3 (N)
    const int fr   = l & 15;
    const int quad = l >> 4;

    f32x4 acc[8][4];
    const f32x4 vzero = {0.f, 0.f, 0.f, 0.f};
#pragma unroll
    for (int i = 0; i < 8; ++i)
#pragma unroll
        for (int j = 0; j < 4; ++j) acc[i][j] = vzero;

    const int sA = (m0 + w * 16 + fr) * 32 + (quad << 3);
    const int sB = (n0 + w * 16 + fr) * 32 + (quad << 3);

    auto stageA = [&](int u) {
        const int  d  = (u & 3) * 16384 + w * 512;
        const long po = (long)u * (M_TOT * 32);
        gload16(A + po + sA, lds + d);
        gload16(A + po + sA + 4096, lds + d + 4096);    // rows +128
    };
    auto stageB = [&](int u) {
        const int  d  = (u & 3) * 16384 + 8192 + w * 512;
        const long po = (long)u * (NB * 32);
        gload16(Bm + po + sB, lds + d);
        gload16(Bm + po + sB + 4096, lds + d + 4096);   // rows +128
    };

    const int rA = wm * 4096 + l * 8;          // + slot*16384 + i*512
    const int rB = 8192 + wn * 2048 + l * 8;   // + slot*16384 + j*512

    stageA(0); stageB(0);
    stageA(1); stageB(1);
    stageA(2); stageB(2);
    asm volatile("s_waitcnt vmcnt(8)" ::: "memory");
    __builtin_amdgcn_s_barrier();

    for (int u = 0; u < 32; ++u) {
        const int sb = (u & 3) * 16384;
        bf16x8 af[4], bf[4];

#pragma unroll
        for (int j = 0; j < 4; ++j) bf[j] = *(const bf16x8*)(lds + sb + rB + j * 512);
#pragma unroll
        for (int i = 0; i < 4; ++i) af[i] = *(const bf16x8*)(lds + sb + rA + i * 512);
        if (u < 29) stageA(u + 3);
        __builtin_amdgcn_s_barrier();
        __builtin_amdgcn_s_setprio(1);
#pragma unroll
        for (int j = 0; j < 4; ++j)
#pragma unroll
            for (int i = 0; i < 4; ++i)
                acc[i][j] = __builtin_amdgcn_mfma_f32_16x16x32_bf16(
                    af[i], bf[j], acc[i][j], 0, 0, 0);
        __builtin_amdgcn_s_setprio(0);
        __builtin_amdgcn_s_barrier();

#pragma unroll
        for (int i = 0; i < 4; ++i) af[i] = *(const bf16x8*)(lds + sb + rA + (4 + i) * 512);
        if (u < 29) stageB(u + 3);
        __builtin_amdgcn_s_barrier();
        __builtin_amdgcn_s_setprio(1);
#pragma unroll
        for (int j = 0; j < 4; ++j)
#pragma unroll
            for (int i = 0; i < 4; ++i)
                acc[4 + i][j] = __builtin_amdgcn_mfma_f32_16x16x32_bf16(
                    af[i], bf[j], acc[4 + i][j], 0, 0, 0);
        __builtin_amdgcn_s_setprio(0);
        if (u < 29)       { asm volatile("s_waitcnt vmcnt(8)" ::: "memory"); }
        else if (u == 29) { asm volatile("s_waitcnt vmcnt(4)" ::: "memory"); }
        else if (u == 30) { asm volatile("s_waitcnt vmcnt(0)" ::: "memory"); }
        __builtin_amdgcn_sched_barrier(0);
        __builtin_amdgcn_s_barrier();
    }
    // final barrier above: all waves done with LDS -> safe to reuse as bounce

    if (EPI == 0) {
        // ---- bounce: 256 rows x 128 v-cols bf16, row stride 128, swizzled ----
        ushort_t* bb = lds;
#pragma unroll
        for (int i = 0; i < 8; ++i)
#pragma unroll
            for (int jp = 0; jp < 2; ++jp) {
                const int colL = wn * 32 + jp * 16 + fr;       // 0..127
                const int chB  = colL >> 3;                    // 0..15
#pragma unroll
                for (int r = 0; r < 4; ++r) {
                    const int rowL = wm * 128 + i * 16 + quad * 4 + r;
                    const int sw   = (chB & 8) | ((chB ^ rowL) & 7);
                    float v = acc[i][2 * jp][r];
                    float g = acc[i][2 * jp + 1][r];
                    float gate = g / (1.0f + __expf(-g));      // silu
                    bb[rowL * 128 + sw * 8 + (colL & 7)] = f32_to_bf16(v * gate);
                }
            }
        __builtin_amdgcn_s_barrier();
        // ---- coalesced stream-out to k-tiled gated ----
#pragma unroll
        for (int s = 0; s < 2; ++s) {
            const int p   = tid & 3;
            const int row = (tid >> 2) + s * 128;
            int4 t0[4];
#pragma unroll
            for (int k = 0; k < 4; ++k) {
                const int ch = p * 4 + k;
                const int sw = (ch & 8) | ((ch ^ row) & 7);
                t0[k] = *(const int4*)(bb + row * 128 + sw * 8);
            }
            const long gb = ((long)((n0 >> 6) + p) * M_TOT + (m0 + row)) * 32;
#pragma unroll
            for (int k = 0; k < 4; ++k)
                *(int4*)(out0 + gb + k * 8) = t0[k];
        }
    } else {
        // ---- bounce: 256 x 256 bf16 (128 KB), row stride 256, swizzled ----
        ushort_t* bb = lds;
#pragma unroll
        for (int i = 0; i < 8; ++i)
#pragma unroll
            for (int j = 0; j < 4; ++j) {
                const int colL = wn * 64 + j * 16 + fr;        // 0..255
                const int chB  = colL >> 3;                    // 0..31
#pragma unroll
                for (int r = 0; r < 4; ++r) {
                    const int rowL = wm * 128 + i * 16 + quad * 4 + r;
                    const int sw   = (chB & 24) | ((chB ^ rowL) & 7);
                    bb[rowL * 256 + sw * 8 + (colL & 7)] = f32_to_bf16(acc[i][j][r]);
                }
            }
        __builtin_amdgcn_s_barrier();
        // ---- coalesced stream-out to row-major proj ----
#pragma unroll
        for (int s = 0; s < 4; ++s) {
            const int p   = tid & 7;
            const int row = (tid >> 3) + s * 64;
            int4 t0[4];
#pragma unroll
            for (int k = 0; k < 4; ++k) {
                const int ch = p * 4 + k;
                const int sw = (ch & 24) | ((ch ^ row) & 7);
                t0[k] = *(const int4*)(bb + row * 256 + sw * 8);
            }
            const long po = (long)(m0 + row) * DM + n0 + p * 32;
#pragma unroll
            for (int k = 0; k < 4; ++k)
                *(int4*)(out0 + po + k * 8) = t0[k];
        }
    }
}

// ---------------- LayerNorm over rows: out = LN(proj + x) ----------------
// proj row-major bf16; x from k-tiled xkt (row slice = 32 chunks of 64 B).
// bf16(proj)+bf16(x) matches r5's passing ln_rows3 pattern (absmax 0.03125).
__global__ __launch_bounds__(256) void ln_rows2(const ushort_t* __restrict__ proj,
                                                const ushort_t* __restrict__ xkt,
                                                const float* __restrict__ gamma,
                                                const float* __restrict__ beta,
                                                float* __restrict__ out)
{
    const int row = blockIdx.x;
    const int tid = threadIdx.x;
    const int wave = tid >> 6, lane = tid & 63;

    ushort4 up = ((const ushort4*)(proj + (long)row * DM))[tid];
    const long xo = ((long)(tid >> 3) * M_TOT + row) * 32 + (tid & 7) * 4;
    ushort4 ux = *(const ushort4*)(xkt + xo);

    float p0 = bf16_to_f32(up.x) + bf16_to_f32(ux.x);
    float p1 = bf16_to_f32(up.y) + bf16_to_f32(ux.y);
    float p2 = bf16_to_f32(up.z) + bf16_to_f32(ux.z);
    float p3 = bf16_to_f32(up.w) + bf16_to_f32(ux.w);

    float s  = p0 + p1 + p2 + p3;
    float ss = p0 * p0 + p1 * p1 + p2 * p2 + p3 * p3;
#pragma unroll
    for (int off = 32; off > 0; off >>= 1) {
        s  += __shfl_down(s, off);
        ss += __shfl_down(ss, off);
    }
    __shared__ float red[8];
    __shared__ float mb[2];
    if (lane == 0) { red[wave] = s; red[4 + wave] = ss; }
    __syncthreads();
    if (tid == 0) {
        float S  = red[0] + red[1] + red[2] + red[3];
        float SS = red[4] + red[5] + red[6] + red[7];
        float mean = S * (1.0f / 1024.0f);
        float var  = SS * (1.0f / 1024.0f) - mean * mean;
        mb[0] = mean;
        mb[1] = rsqrtf(var + 1e-5f);
    }
    __syncthreads();
    const float mean = mb[0], rs = mb[1];

    float4 gm = ((const float4*)gamma)[tid];
    float4 bt = ((const float4*)beta)[tid];
    float4 o;
    o.x = (p0 - mean) * rs * gm.x + bt.x;
    o.y = (p1 - mean) * rs * gm.y + bt.y;
    o.z = (p2 - mean) * rs * gm.z + bt.z;
    o.w = (p3 - mean) * rs * gm.w + bt.w;
    ((float4*)(out + (long)row * DM))[tid] = o;
}

// ---------------- launch ----------------
extern "C" void kernel_launch(void* const* d_in, const int* in_sizes, int n_in,
                              void* d_out, int out_size, void* d_ws, size_t ws_size,
                              hipStream_t stream) {
    // setup_inputs order: x, W_Q, W_K, W_V, W_g, W_alpha, W_O, ln_gamma, ln_beta
    const float* x     = (const float*)d_in[0];
    const float* WV    = (const float*)d_in[3];
    const float* WG    = (const float*)d_in[4];
    const float* WO    = (const float*)d_in[6];
    const float* gamma = (const float*)d_in[7];
    const float* beta  = (const float*)d_in[8];
    float* out = (float*)d_out;

    // ws layout: xkt 32MB | gated 32MB | wcat 4MB | wob 2MB | proj 32MB
    const size_t SZX = (size_t)M_TOT * DM * 2;        // 32 MB
    const size_t SZW = (size_t)DM * DM * 2;           // 2 MB
    char* ws = (char*)d_ws;
    ushort_t* xkt   = (ushort_t*)ws;
    ushort_t* gated = (ushort_t*)(ws + SZX);
    ushort_t* wcat  = (ushort_t*)(ws + 2 * SZX);
    ushort_t* wob   = (ushort_t*)(ws + 2 * SZX + 2 * SZW);
    ushort_t* proj  = (ushort_t*)(ws + 2 * SZX + 3 * SZW);

    static bool attr_set = false;
    if (!attr_set) {
        hipFuncSetAttribute((const void*)&gemmS<0, 2048>,
                            hipFuncAttributeMaxDynamicSharedMemorySize, 131072);
        hipFuncSetAttribute((const void*)&gemmS<1, 1024>,
                            hipFuncAttributeMaxDynamicSharedMemorySize, 131072);
        attr_set = true;
    }

    // chunks: x 2,097,152 + wcat 262,144 + wob 131,072 = 2,490,368 -> 9728 blocks
    cvt_all<<<9728, 256, 0, stream>>>(x, WV, WG, WO, xkt, wcat, wob);

    // V&g cat-GEMM: M=16384 (64 m-blocks), N_cat=2048 (8 n-blocks) -> 512
    gemmS<0, 2048><<<512, 512, 131072, stream>>>(xkt, wcat, gated, 3);
    // O-proj: M=16384 (64), N=1024 (4 n-blocks) -> 256
    gemmS<1, 1024><<<256, 512, 131072, stream>>>(gated, wob, proj, 2);

    ln_rows2<<<M_TOT, 256, 0, stream>>>(proj, xkt, gamma, beta, out);
}